// Round 5
// baseline (601.620 us; speedup 1.0000x reference)
//
#include <hip/hip_runtime.h>
#include <stdint.h>

// StochLinear: out[b,n] = 2048 - 0.25 * popcount(A_bits[b] ^ W_bits[n]) + bias[n]
// A/W bits: JAX threefry2x32, partitionable mode (confirmed exact in round 2).
// B=4096, K=2048, N=2048, L=8 -> 256 u64 words per packed row.

#define B_DIM 4096
#define K_DIM 2048
#define N_DIM 2048
#define WORDS 256  // L*K/64

typedef unsigned long long u64;

__host__ __device__ static inline void tf2x32(uint32_t ks0, uint32_t ks1,
                                              uint32_t x0, uint32_t x1,
                                              uint32_t* o0, uint32_t* o1) {
  uint32_t ks2 = ks0 ^ ks1 ^ 0x1BD11BDAu;
  x0 += ks0; x1 += ks1;
#define TF_RND(r) { x0 += x1; x1 = (x1 << (r)) | (x1 >> (32 - (r))); x1 ^= x0; }
  TF_RND(13) TF_RND(15) TF_RND(26) TF_RND(6)
  x0 += ks1; x1 += ks2 + 1u;
  TF_RND(17) TF_RND(29) TF_RND(16) TF_RND(24)
  x0 += ks2; x1 += ks0 + 2u;
  TF_RND(13) TF_RND(15) TF_RND(26) TF_RND(6)
  x0 += ks0; x1 += ks1 + 3u;
  TF_RND(17) TF_RND(29) TF_RND(16) TF_RND(24)
  x0 += ks1; x1 += ks2 + 4u;
  TF_RND(13) TF_RND(15) TF_RND(26) TF_RND(6)
  x0 += ks2; x1 += ks0 + 5u;
  *o0 = x0; *o1 = x1;
#undef TF_RND
}

// One block per row b. 4 waves; wave wv covers kw = wv*8+i (i<8); per (kw,l):
// one threefry per lane, __ballot packs 64 bits -> Ap[b][l*32+kw].
// A element (l,b,k): linear idx = (l*4096+b)*2048+k = l*2^23 + b*2048 + k (hi32 = 0).
__global__ __launch_bounds__(256) void stoch_bits_x(const float* __restrict__ x,
                                                    u64* __restrict__ Ap,
                                                    uint32_t k0, uint32_t k1) {
  const unsigned b = blockIdx.x;
  const unsigned lane = threadIdx.x & 63u;
  const unsigned wv = threadIdx.x >> 6;
  const float* xrow = x + (size_t)b * K_DIM;
  u64* arow = Ap + (size_t)b * WORDS;
#pragma unroll 1
  for (int i = 0; i < 8; ++i) {
    const unsigned kw = wv * 8u + (unsigned)i;
    const unsigned k = (kw << 6) + lane;
    const float v = xrow[k];
    const float p = fminf(fmaxf((v + 1.0f) * 0.5f, 0.0f), 1.0f);
    const float t = p * 8388608.0f;  // p * 2^23 (exact); u<p <=> (f32)(bits>>9) < t
    const uint32_t base = b * 2048u + k;
    u64 wbuf[8];
#pragma unroll
    for (int l = 0; l < 8; ++l) {
      uint32_t idx = base + ((uint32_t)l << 23);
      uint32_t o0, o1;
      tf2x32(k0, k1, 0u, idx, &o0, &o1);
      uint32_t m = (o0 ^ o1) >> 9;
      wbuf[l] = __ballot((float)m < t);
    }
    if (lane == 0) {
#pragma unroll
      for (int l = 0; l < 8; ++l) arow[(l << 5) + kw] = wbuf[l];
    }
  }
}

// One block per row n of weight (W^T column).
// W element (l,k,n): linear idx = (l*2048+k)*2048+n = l*2^22 + k*2048 + n.
__global__ __launch_bounds__(256) void stoch_bits_w(const float* __restrict__ wgt,
                                                    u64* __restrict__ Wp,
                                                    uint32_t k0, uint32_t k1) {
  const unsigned n = blockIdx.x;
  const unsigned lane = threadIdx.x & 63u;
  const unsigned wv = threadIdx.x >> 6;
  const float* wrow = wgt + (size_t)n * K_DIM;
  u64* prow = Wp + (size_t)n * WORDS;
#pragma unroll 1
  for (int i = 0; i < 8; ++i) {
    const unsigned kw = wv * 8u + (unsigned)i;
    const unsigned k = (kw << 6) + lane;
    const float v = wrow[k];
    const float p = fminf(fmaxf((v + 1.0f) * 0.5f, 0.0f), 1.0f);
    const float t = p * 8388608.0f;
    const uint32_t base = k * 2048u + n;
    u64 wbuf[8];
#pragma unroll
    for (int l = 0; l < 8; ++l) {
      uint32_t idx = base + ((uint32_t)l << 22);  // FIXED: l*2^22 (was l*2^23)
      uint32_t o0, o1;
      tf2x32(k0, k1, 0u, idx, &o0, &o1);
      uint32_t m = (o0 ^ o1) >> 9;
      wbuf[l] = __ballot((float)m < t);
    }
    if (lane == 0) {
#pragma unroll
      for (int l = 0; l < 8; ++l) prow[(l << 5) + kw] = wbuf[l];
    }
  }
}

// XOR-popcount GEMM: 64x128 output tile per block, 4 rows x 8 cols per thread.
// Thread (tx,ty): rows ty*4+i, cols tx+16*j -> bv reads hit 16 consecutive LDS
// rows (stride 33 u64 = 66 dw = 2 mod 32) = 16 distinct even bank-starts,
// conflict-free (vs 4-way with the 4tx+j mapping).
__global__ __launch_bounds__(256) void xnor_gemm(const u64* __restrict__ Ap,
                                                 const u64* __restrict__ Wp,
                                                 const float* __restrict__ bias,
                                                 float* __restrict__ out) {
  __shared__ u64 As[64][33];
  __shared__ u64 Ws[128][33];
  const int tid = threadIdx.x;
  const int brow = blockIdx.y << 6;
  const int bcol = blockIdx.x << 7;
  const int tx = tid & 15, ty = tid >> 4;
  uint32_t cnt[4][8] = {};
#pragma unroll 1
  for (int c = 0; c < 8; ++c) {
    if (c) __syncthreads();
#pragma unroll
    for (int i = 0; i < 8; ++i) {
      int idx = tid + (i << 8);
      int r = idx >> 5, w = idx & 31;
      As[r][w] = Ap[(size_t)(brow + r) * WORDS + (c << 5) + w];
    }
#pragma unroll
    for (int i = 0; i < 16; ++i) {
      int idx = tid + (i << 8);
      int r = idx >> 5, w = idx & 31;
      Ws[r][w] = Wp[(size_t)(bcol + r) * WORDS + (c << 5) + w];
    }
    __syncthreads();
#pragma unroll 2
    for (int w = 0; w < 32; ++w) {
      u64 av[4], bv[8];
#pragma unroll
      for (int i = 0; i < 4; ++i) av[i] = As[(ty << 2) + i][w];
#pragma unroll
      for (int j = 0; j < 8; ++j) bv[j] = Ws[tx + (j << 4)][w];
#pragma unroll
      for (int i = 0; i < 4; ++i)
#pragma unroll
        for (int j = 0; j < 8; ++j)
          cnt[i][j] += (uint32_t)__popcll(av[i] ^ bv[j]);
    }
  }
#pragma unroll
  for (int i = 0; i < 4; ++i) {
    int r = brow + (ty << 2) + i;
#pragma unroll
    for (int j = 0; j < 8; ++j) {
      int n = bcol + tx + (j << 4);
      out[(size_t)r * N_DIM + n] = 2048.0f - 0.25f * (float)cnt[i][j] + bias[n];
    }
  }
}

extern "C" void kernel_launch(void* const* d_in, const int* in_sizes, int n_in,
                              void* d_out, int out_size, void* d_ws, size_t ws_size,
                              hipStream_t stream) {
  const float* x = (const float*)d_in[0];
  const float* wgt = (const float*)d_in[1];
  const float* bias = (const float*)d_in[2];
  float* out = (float*)d_out;

  u64* Ap = (u64*)d_ws;                       // 4096*256*8 = 8 MB
  u64* Wp = Ap + (size_t)B_DIM * WORDS;       // 2048*256*8 = 4 MB

  // key(42) = (0,42); partitionable split: kA = tf((0,42),(0,0)), kB = tf((0,42),(0,1))
  uint32_t kA0, kA1, kB0, kB1;
  tf2x32(0u, 42u, 0u, 0u, &kA0, &kA1);
  tf2x32(0u, 42u, 0u, 1u, &kB0, &kB1);

  stoch_bits_x<<<B_DIM, 256, 0, stream>>>(x, Ap, kA0, kA1);
  stoch_bits_w<<<N_DIM, 256, 0, stream>>>(wgt, Wp, kB0, kB1);
  dim3 grid(N_DIM / 128, B_DIM / 64);
  xnor_gemm<<<grid, 256, 0, stream>>>(Ap, Wp, bias, out);
  (void)in_sizes; (void)n_in; (void)out_size; (void)ws_size;
}

// Round 8
// 561.843 us; speedup vs baseline: 1.0708x; 1.0708x over previous
//
#include <hip/hip_runtime.h>
#include <stdint.h>

// StochLinear: out[b,n] = 2048 - 0.25 * popcount(A_bits[b] ^ W_bits[n]) + bias[n]
// A/W bits: JAX threefry2x32, partitionable mode (bit-exact, verified rounds 2/5).
// B=4096, K=2048, N=2048, L=8 -> 256 u64 words per packed row.

#define B_DIM 4096
#define K_DIM 2048
#define N_DIM 2048
#define WORDS 256  // L*K/64

typedef unsigned long long u64;

__host__ __device__ static inline void tf2x32(uint32_t ks0, uint32_t ks1,
                                              uint32_t x0, uint32_t x1,
                                              uint32_t* o0, uint32_t* o1) {
  uint32_t ks2 = ks0 ^ ks1 ^ 0x1BD11BDAu;
  x0 += ks0; x1 += ks1;
#define TF_RND(r) { x0 += x1; x1 = (x1 << (r)) | (x1 >> (32 - (r))); x1 ^= x0; }
  TF_RND(13) TF_RND(15) TF_RND(26) TF_RND(6)
  x0 += ks1; x1 += ks2 + 1u;
  TF_RND(17) TF_RND(29) TF_RND(16) TF_RND(24)
  x0 += ks2; x1 += ks0 + 2u;
  TF_RND(13) TF_RND(15) TF_RND(26) TF_RND(6)
  x0 += ks0; x1 += ks1 + 3u;
  TF_RND(17) TF_RND(29) TF_RND(16) TF_RND(24)
  x0 += ks1; x1 += ks2 + 4u;
  TF_RND(13) TF_RND(15) TF_RND(26) TF_RND(6)
  x0 += ks2; x1 += ks0 + 5u;
  *o0 = x0; *o1 = x1;
#undef TF_RND
}

// Fused bit-gen: blocks [0,4096) -> x rows (Ap), [4096,6144) -> weight rows (Wp).
// Per (row): 4 waves; wave wv covers kw = wv*8+i; one threefry per (l,lane),
// __ballot packs 64 bits -> dst[row][l*32+kw].
// x element (l,b,k): counter = l*2^23 + b*2048 + k.
// w element (l,k,n): counter = l*2^22 + k*2048 + n.   (both hi32 = 0)
__global__ __launch_bounds__(256) void stoch_bits(const float* __restrict__ x,
                                                  const float* __restrict__ wgt,
                                                  u64* __restrict__ Ap,
                                                  u64* __restrict__ Wp,
                                                  uint32_t xk0, uint32_t xk1,
                                                  uint32_t wk0, uint32_t wk1) {
  const unsigned blk = blockIdx.x;
  const bool isW = blk >= (unsigned)B_DIM;
  const unsigned row = isW ? (blk - (unsigned)B_DIM) : blk;
  const float* src = (isW ? wgt : x) + (size_t)row * K_DIM;
  u64* dst = (isW ? Wp : Ap) + (size_t)row * WORDS;
  const uint32_t k0 = isW ? wk0 : xk0;
  const uint32_t k1 = isW ? wk1 : xk1;
  const unsigned lane = threadIdx.x & 63u;
  const unsigned wv = threadIdx.x >> 6;
#pragma unroll 1
  for (int i = 0; i < 8; ++i) {
    const unsigned kw = wv * 8u + (unsigned)i;
    const unsigned k = (kw << 6) + lane;
    const float v = src[k];
    const float p = fminf(fmaxf((v + 1.0f) * 0.5f, 0.0f), 1.0f);
    const float t = p * 8388608.0f;  // p * 2^23 (exact); u<p <=> (f32)(bits>>9) < t
    const uint32_t base = isW ? (k * 2048u + row) : (row * 2048u + k);
    u64 wbuf[8];
#pragma unroll
    for (int l = 0; l < 8; ++l) {
      uint32_t idx = base + (isW ? ((uint32_t)l << 22) : ((uint32_t)l << 23));
      uint32_t o0, o1;
      tf2x32(k0, k1, 0u, idx, &o0, &o1);
      uint32_t m = (o0 ^ o1) >> 9;
      wbuf[l] = __ballot((float)m < t);
    }
    if (lane == 0) {
#pragma unroll
      for (int l = 0; l < 8; ++l) dst[(l << 5) + kw] = wbuf[l];
    }
  }
}

// XOR-popcount GEMM: 64x128 tile, 4 rows x 8 cols per thread.
// u32-domain inner loop: uint4 LDS reads (ds_read_b128), per-dword
// s = __popc(a^b) + s  -> accumulate-form v_bcnt_u32_b32 (4 VALU ops / u64).
// Row pad 34 u64 (68 dw): 16B-aligned b128 at even word offsets; bv rows
// tx+16j -> bank-quad starts 4*tx mod 32 (tx,tx+8 pair = 2-way, free);
// av rows 4ty+i -> 2-way broadcast, free.
__global__ __launch_bounds__(256) void xnor_gemm(const u64* __restrict__ Ap,
                                                 const u64* __restrict__ Wp,
                                                 const float* __restrict__ bias,
                                                 float* __restrict__ out) {
  __shared__ u64 As[64][34];
  __shared__ u64 Ws[128][34];
  const int tid = threadIdx.x;
  const int brow = blockIdx.y << 6;
  const int bcol = blockIdx.x << 7;
  const int tx = tid & 15, ty = tid >> 4;
  uint32_t cnt[4][8] = {};
#pragma unroll 1
  for (int c = 0; c < 8; ++c) {
    if (c) __syncthreads();
#pragma unroll
    for (int i = 0; i < 4; ++i) {  // A: 64 rows x 16 u64-pairs = 1024 uint4
      int q = tid + (i << 8);
      int r = q >> 4, wp = q & 15;
      *(uint4*)&As[r][wp << 1] =
          *(const uint4*)&Ap[(size_t)(brow + r) * WORDS + (c << 5) + (wp << 1)];
    }
#pragma unroll
    for (int i = 0; i < 8; ++i) {  // W: 128 rows x 16 pairs = 2048 uint4
      int q = tid + (i << 8);
      int r = q >> 4, wp = q & 15;
      *(uint4*)&Ws[r][wp << 1] =
          *(const uint4*)&Wp[(size_t)(bcol + r) * WORDS + (c << 5) + (wp << 1)];
    }
    __syncthreads();
#pragma unroll 1
    for (int wp = 0; wp < 16; ++wp) {
      uint4 av[4], bv[8];
#pragma unroll
      for (int i = 0; i < 4; ++i)
        av[i] = *(const uint4*)&As[(ty << 2) + i][wp << 1];
#pragma unroll
      for (int j = 0; j < 8; ++j)
        bv[j] = *(const uint4*)&Ws[tx + (j << 4)][wp << 1];
#pragma unroll
      for (int i = 0; i < 4; ++i)
#pragma unroll
        for (int j = 0; j < 8; ++j) {
          uint32_t s = cnt[i][j];
          s = (uint32_t)__popc(av[i].x ^ bv[j].x) + s;
          s = (uint32_t)__popc(av[i].y ^ bv[j].y) + s;
          s = (uint32_t)__popc(av[i].z ^ bv[j].z) + s;
          s = (uint32_t)__popc(av[i].w ^ bv[j].w) + s;
          cnt[i][j] = s;
        }
    }
  }
#pragma unroll
  for (int i = 0; i < 4; ++i) {
    int r = brow + (ty << 2) + i;
#pragma unroll
    for (int j = 0; j < 8; ++j) {
      int n = bcol + tx + (j << 4);
      out[(size_t)r * N_DIM + n] = 2048.0f - 0.25f * (float)cnt[i][j] + bias[n];
    }
  }
}

extern "C" void kernel_launch(void* const* d_in, const int* in_sizes, int n_in,
                              void* d_out, int out_size, void* d_ws, size_t ws_size,
                              hipStream_t stream) {
  const float* x = (const float*)d_in[0];
  const float* wgt = (const float*)d_in[1];
  const float* bias = (const float*)d_in[2];
  float* out = (float*)d_out;

  u64* Ap = (u64*)d_ws;                       // 4096*256*8 = 8 MB
  u64* Wp = Ap + (size_t)B_DIM * WORDS;       // 2048*256*8 = 4 MB

  // key(42) = (0,42); partitionable split: kA = tf((0,42),(0,0)), kB = tf((0,42),(0,1))
  uint32_t kA0, kA1, kB0, kB1;
  tf2x32(0u, 42u, 0u, 0u, &kA0, &kA1);
  tf2x32(0u, 42u, 0u, 1u, &kB0, &kB1);

  stoch_bits<<<B_DIM + N_DIM, 256, 0, stream>>>(x, wgt, Ap, Wp, kA0, kA1, kB0, kB1);
  dim3 grid(N_DIM / 128, B_DIM / 64);
  xnor_gemm<<<grid, 256, 0, stream>>>(Ap, Wp, bias, out);
  (void)in_sizes; (void)n_in; (void)out_size; (void)ws_size;
}

// Round 9
// 523.092 us; speedup vs baseline: 1.1501x; 1.0741x over previous
//
#include <hip/hip_runtime.h>
#include <stdint.h>

// StochLinear: out[b,n] = 2048 - 0.25 * popcount(A_bits[b] ^ W_bits[n]) + bias[n]
// A/W bits: JAX threefry2x32, partitionable mode (bit-exact, verified rounds 2/5/8).
// B=4096, K=2048, N=2048, L=8 -> 256 u64 words per packed row.

#define B_DIM 4096
#define K_DIM 2048
#define N_DIM 2048
#define WORDS 256  // L*K/64

typedef unsigned long long u64;

__host__ __device__ static inline void tf2x32(uint32_t ks0, uint32_t ks1,
                                              uint32_t x0, uint32_t x1,
                                              uint32_t* o0, uint32_t* o1) {
  uint32_t ks2 = ks0 ^ ks1 ^ 0x1BD11BDAu;
  x0 += ks0; x1 += ks1;
#define TF_RND(r) { x0 += x1; x1 = (x1 << (r)) | (x1 >> (32 - (r))); x1 ^= x0; }
  TF_RND(13) TF_RND(15) TF_RND(26) TF_RND(6)
  x0 += ks1; x1 += ks2 + 1u;
  TF_RND(17) TF_RND(29) TF_RND(16) TF_RND(24)
  x0 += ks2; x1 += ks0 + 2u;
  TF_RND(13) TF_RND(15) TF_RND(26) TF_RND(6)
  x0 += ks0; x1 += ks1 + 3u;
  TF_RND(17) TF_RND(29) TF_RND(16) TF_RND(24)
  x0 += ks1; x1 += ks2 + 4u;
  TF_RND(13) TF_RND(15) TF_RND(26) TF_RND(6)
  x0 += ks2; x1 += ks0 + 5u;
  *o0 = x0; *o1 = x1;
#undef TF_RND
}

// Fused bit-gen (unchanged from round 8, bit-exact verified):
// blocks [0,4096) -> x rows (Ap), [4096,6144) -> weight rows (Wp).
// x element (l,b,k): counter = l*2^23 + b*2048 + k.
// w element (l,k,n): counter = l*2^22 + k*2048 + n.   (both hi32 = 0)
__global__ __launch_bounds__(256) void stoch_bits(const float* __restrict__ x,
                                                  const float* __restrict__ wgt,
                                                  u64* __restrict__ Ap,
                                                  u64* __restrict__ Wp,
                                                  uint32_t xk0, uint32_t xk1,
                                                  uint32_t wk0, uint32_t wk1) {
  const unsigned blk = blockIdx.x;
  const bool isW = blk >= (unsigned)B_DIM;
  const unsigned row = isW ? (blk - (unsigned)B_DIM) : blk;
  const float* src = (isW ? wgt : x) + (size_t)row * K_DIM;
  u64* dst = (isW ? Wp : Ap) + (size_t)row * WORDS;
  const uint32_t k0 = isW ? wk0 : xk0;
  const uint32_t k1 = isW ? wk1 : xk1;
  const unsigned lane = threadIdx.x & 63u;
  const unsigned wv = threadIdx.x >> 6;
#pragma unroll 1
  for (int i = 0; i < 8; ++i) {
    const unsigned kw = wv * 8u + (unsigned)i;
    const unsigned k = (kw << 6) + lane;
    const float v = src[k];
    const float p = fminf(fmaxf((v + 1.0f) * 0.5f, 0.0f), 1.0f);
    const float t = p * 8388608.0f;  // p * 2^23 (exact); u<p <=> (f32)(bits>>9) < t
    const uint32_t base = isW ? (k * 2048u + row) : (row * 2048u + k);
    u64 wbuf[8];
#pragma unroll
    for (int l = 0; l < 8; ++l) {
      uint32_t idx = base + (isW ? ((uint32_t)l << 22) : ((uint32_t)l << 23));
      uint32_t o0, o1;
      tf2x32(k0, k1, 0u, idx, &o0, &o1);
      uint32_t m = (o0 ^ o1) >> 9;
      wbuf[l] = __ballot((float)m < t);
    }
    if (lane == 0) {
#pragma unroll
      for (int l = 0; l < 8; ++l) dst[(l << 5) + kw] = wbuf[l];
    }
  }
}

// XOR-popcount GEMM: 128x128 tile, 8 rows x 8 cols per thread.
// Rows ty+16i, cols tx+16j (interleaved map):
//   av reads: 4 distinct rows (stride 68 dw = 4 mod 32) -> bank-quads {0,4,8,12},
//             16-lane broadcast -> conflict-free.
//   bv reads: 16 rows, quad-starts 4*tx mod 32 -> tx/tx+8 2-way (free, m136).
// Inner product: v_xor_b32 (C) + inline-asm v_bcnt_u32_b32 accumulate
// (D = popcount(S0) + S1) -> exactly 4 VALU ops per u64-product.
// Grid = 16x32 = 512 blocks = exactly 2/CU (69.6 KB LDS), no tail.
__global__ __launch_bounds__(256) void xnor_gemm(const u64* __restrict__ Ap,
                                                 const u64* __restrict__ Wp,
                                                 const float* __restrict__ bias,
                                                 float* __restrict__ out) {
  __shared__ u64 As[128][34];
  __shared__ u64 Ws[128][34];
  const int tid = threadIdx.x;
  const int brow = blockIdx.y << 7;
  const int bcol = blockIdx.x << 7;
  const int tx = tid & 15, ty = tid >> 4;
  uint32_t cnt[8][8] = {};
#pragma unroll 1
  for (int c = 0; c < 8; ++c) {
    if (c) __syncthreads();
#pragma unroll
    for (int i = 0; i < 8; ++i) {  // A: 128 rows x 16 uint4 = 2048
      int q = tid + (i << 8);
      int r = q >> 4, wp = q & 15;
      *(uint4*)&As[r][wp << 1] =
          *(const uint4*)&Ap[(size_t)(brow + r) * WORDS + (c << 5) + (wp << 1)];
    }
#pragma unroll
    for (int i = 0; i < 8; ++i) {  // W: 128 rows x 16 uint4 = 2048
      int q = tid + (i << 8);
      int r = q >> 4, wp = q & 15;
      *(uint4*)&Ws[r][wp << 1] =
          *(const uint4*)&Wp[(size_t)(bcol + r) * WORDS + (c << 5) + (wp << 1)];
    }
    __syncthreads();
#pragma unroll 2
    for (int wp = 0; wp < 16; ++wp) {
      uint4 av[8];
#pragma unroll
      for (int i = 0; i < 8; ++i)
        av[i] = *(const uint4*)&As[ty + (i << 4)][wp << 1];
#pragma unroll
      for (int j = 0; j < 8; ++j) {
        uint4 bv = *(const uint4*)&Ws[tx + (j << 4)][wp << 1];
#pragma unroll
        for (int i = 0; i < 8; ++i) {
          uint32_t t0 = av[i].x ^ bv.x;
          uint32_t t1 = av[i].y ^ bv.y;
          uint32_t t2 = av[i].z ^ bv.z;
          uint32_t t3 = av[i].w ^ bv.w;
          asm("v_bcnt_u32_b32 %0, %1, %0" : "+v"(cnt[i][j]) : "v"(t0));
          asm("v_bcnt_u32_b32 %0, %1, %0" : "+v"(cnt[i][j]) : "v"(t1));
          asm("v_bcnt_u32_b32 %0, %1, %0" : "+v"(cnt[i][j]) : "v"(t2));
          asm("v_bcnt_u32_b32 %0, %1, %0" : "+v"(cnt[i][j]) : "v"(t3));
        }
      }
    }
  }
#pragma unroll
  for (int i = 0; i < 8; ++i) {
    int r = brow + ty + (i << 4);
#pragma unroll
    for (int j = 0; j < 8; ++j) {
      int n = bcol + tx + (j << 4);
      out[(size_t)r * N_DIM + n] = 2048.0f - 0.25f * (float)cnt[i][j] + bias[n];
    }
  }
}

extern "C" void kernel_launch(void* const* d_in, const int* in_sizes, int n_in,
                              void* d_out, int out_size, void* d_ws, size_t ws_size,
                              hipStream_t stream) {
  const float* x = (const float*)d_in[0];
  const float* wgt = (const float*)d_in[1];
  const float* bias = (const float*)d_in[2];
  float* out = (float*)d_out;

  u64* Ap = (u64*)d_ws;                       // 4096*256*8 = 8 MB
  u64* Wp = Ap + (size_t)B_DIM * WORDS;       // 2048*256*8 = 4 MB

  // key(42) = (0,42); partitionable split: kA = tf((0,42),(0,0)), kB = tf((0,42),(0,1))
  uint32_t kA0, kA1, kB0, kB1;
  tf2x32(0u, 42u, 0u, 0u, &kA0, &kA1);
  tf2x32(0u, 42u, 0u, 1u, &kB0, &kB1);

  stoch_bits<<<B_DIM + N_DIM, 256, 0, stream>>>(x, wgt, Ap, Wp, kA0, kA1, kB0, kB1);
  dim3 grid(N_DIM / 128, B_DIM / 128);
  xnor_gemm<<<grid, 256, 0, stream>>>(Ap, Wp, bias, out);
  (void)in_sizes; (void)n_in; (void)out_size; (void)ws_size;
}

// Round 11
// 501.605 us; speedup vs baseline: 1.1994x; 1.0428x over previous
//
#include <hip/hip_runtime.h>
#include <stdint.h>

// StochLinear: out[b,n] = 2048 - 0.25 * popcount(A_bits[b] ^ W_bits[n]) + bias[n]
// A/W bits: JAX threefry2x32, partitionable mode (bit-exact, verified rounds 2/5/8/9).
// B=4096, K=2048, N=2048, L=8 -> 256 u64 words per packed row.

#define B_DIM 4096
#define K_DIM 2048
#define N_DIM 2048
#define WORDS 256  // L*K/64

typedef unsigned long long u64;

__host__ __device__ static inline void tf2x32(uint32_t ks0, uint32_t ks1,
                                              uint32_t x0, uint32_t x1,
                                              uint32_t* o0, uint32_t* o1) {
  uint32_t ks2 = ks0 ^ ks1 ^ 0x1BD11BDAu;
  x0 += ks0; x1 += ks1;
#define TF_RND(r) { x0 += x1; x1 = (x1 << (r)) | (x1 >> (32 - (r))); x1 ^= x0; }
  TF_RND(13) TF_RND(15) TF_RND(26) TF_RND(6)
  x0 += ks1; x1 += ks2 + 1u;
  TF_RND(17) TF_RND(29) TF_RND(16) TF_RND(24)
  x0 += ks2; x1 += ks0 + 2u;
  TF_RND(13) TF_RND(15) TF_RND(26) TF_RND(6)
  x0 += ks0; x1 += ks1 + 3u;
  TF_RND(17) TF_RND(29) TF_RND(16) TF_RND(24)
  x0 += ks1; x1 += ks2 + 4u;
  TF_RND(13) TF_RND(15) TF_RND(26) TF_RND(6)
  x0 += ks2; x1 += ks0 + 5u;
  *o0 = x0; *o1 = x1;
#undef TF_RND
}

// Fused bit-gen (unchanged, bit-exact verified):
// blocks [0,4096) -> x rows (Ap), [4096,6144) -> weight rows (Wp).
// x element (l,b,k): counter = l*2^23 + b*2048 + k.
// w element (l,k,n): counter = l*2^22 + k*2048 + n.   (both hi32 = 0)
__global__ __launch_bounds__(256) void stoch_bits(const float* __restrict__ x,
                                                  const float* __restrict__ wgt,
                                                  u64* __restrict__ Ap,
                                                  u64* __restrict__ Wp,
                                                  uint32_t xk0, uint32_t xk1,
                                                  uint32_t wk0, uint32_t wk1) {
  const unsigned blk = blockIdx.x;
  const bool isW = blk >= (unsigned)B_DIM;
  const unsigned row = isW ? (blk - (unsigned)B_DIM) : blk;
  const float* src = (isW ? wgt : x) + (size_t)row * K_DIM;
  u64* dst = (isW ? Wp : Ap) + (size_t)row * WORDS;
  const uint32_t k0 = isW ? wk0 : xk0;
  const uint32_t k1 = isW ? wk1 : xk1;
  const unsigned lane = threadIdx.x & 63u;
  const unsigned wv = threadIdx.x >> 6;
#pragma unroll 1
  for (int i = 0; i < 8; ++i) {
    const unsigned kw = wv * 8u + (unsigned)i;
    const unsigned k = (kw << 6) + lane;
    const float v = src[k];
    const float p = fminf(fmaxf((v + 1.0f) * 0.5f, 0.0f), 1.0f);
    const float t = p * 8388608.0f;  // p * 2^23 (exact); u<p <=> (f32)(bits>>9) < t
    const uint32_t base = isW ? (k * 2048u + row) : (row * 2048u + k);
    u64 wbuf[8];
#pragma unroll
    for (int l = 0; l < 8; ++l) {
      uint32_t idx = base + (isW ? ((uint32_t)l << 22) : ((uint32_t)l << 23));
      uint32_t o0, o1;
      tf2x32(k0, k1, 0u, idx, &o0, &o1);
      uint32_t m = (o0 ^ o1) >> 9;
      wbuf[l] = __ballot((float)m < t);
    }
    if (lane == 0) {
#pragma unroll
      for (int l = 0; l < 8; ++l) dst[(l << 5) + kw] = wbuf[l];
    }
  }
}

// XOR-popcount GEMM, occupancy experiment:
// 128x64 tile, CH=16 u64 K-chunks (16 iters), LDS 27.6 KB -> 4 blocks/CU
// (grid 1024 = exactly 4/CU; launch_bounds(256,4) caps VGPR at 128).
// Per thread: 8 rows (ty+16i) x 4 cols (tx+16j).
// Row pad 18 u64 = 144 B (16B-aligned rows; stride 36 dw = 4 mod 32):
//   av: 4 ty-rows -> quad starts {0,4,8,12}, 16-lane broadcast, conflict-free.
//   bv: 16 tx-rows -> starts 4*tx mod 32, tx/tx+8 2-way (free).
// Inner: v_xor_b32 + inline-asm v_bcnt_u32_b32 accumulate = 4 ops/u64.
__global__ __launch_bounds__(256, 4) void xnor_gemm(const u64* __restrict__ Ap,
                                                    const u64* __restrict__ Wp,
                                                    const float* __restrict__ bias,
                                                    float* __restrict__ out) {
  __shared__ u64 As[128][18];
  __shared__ u64 Ws[64][18];
  const int tid = threadIdx.x;
  const int brow = blockIdx.y << 7;
  const int bcol = blockIdx.x << 6;
  const int tx = tid & 15, ty = tid >> 4;
  uint32_t cnt[8][4] = {};
#pragma unroll 1
  for (int c = 0; c < 16; ++c) {
    if (c) __syncthreads();
#pragma unroll
    for (int i = 0; i < 4; ++i) {  // A chunk: 128 rows x 8 uint4 = 1024
      int q = tid + (i << 8);
      int r = q >> 3, c4 = q & 7;
      *(uint4*)&As[r][c4 << 1] =
          *(const uint4*)&Ap[(size_t)(brow + r) * WORDS + (c << 4) + (c4 << 1)];
    }
#pragma unroll
    for (int i = 0; i < 2; ++i) {  // W chunk: 64 rows x 8 uint4 = 512
      int q = tid + (i << 8);
      int r = q >> 3, c4 = q & 7;
      *(uint4*)&Ws[r][c4 << 1] =
          *(const uint4*)&Wp[(size_t)(bcol + r) * WORDS + (c << 4) + (c4 << 1)];
    }
    __syncthreads();
#pragma unroll 2
    for (int wp = 0; wp < 8; ++wp) {
      uint4 av[8], bv[4];
#pragma unroll
      for (int i = 0; i < 8; ++i)
        av[i] = *(const uint4*)&As[ty + (i << 4)][wp << 1];
#pragma unroll
      for (int j = 0; j < 4; ++j)
        bv[j] = *(const uint4*)&Ws[tx + (j << 4)][wp << 1];
#pragma unroll
      for (int i = 0; i < 8; ++i)
#pragma unroll
        for (int j = 0; j < 4; ++j) {
          uint32_t t0 = av[i].x ^ bv[j].x;
          uint32_t t1 = av[i].y ^ bv[j].y;
          uint32_t t2 = av[i].z ^ bv[j].z;
          uint32_t t3 = av[i].w ^ bv[j].w;
          asm("v_bcnt_u32_b32 %0, %1, %0" : "+v"(cnt[i][j]) : "v"(t0));
          asm("v_bcnt_u32_b32 %0, %1, %0" : "+v"(cnt[i][j]) : "v"(t1));
          asm("v_bcnt_u32_b32 %0, %1, %0" : "+v"(cnt[i][j]) : "v"(t2));
          asm("v_bcnt_u32_b32 %0, %1, %0" : "+v"(cnt[i][j]) : "v"(t3));
        }
    }
  }
#pragma unroll
  for (int i = 0; i < 8; ++i) {
    int r = brow + ty + (i << 4);
#pragma unroll
    for (int j = 0; j < 4; ++j) {
      int n = bcol + tx + (j << 4);
      out[(size_t)r * N_DIM + n] = 2048.0f - 0.25f * (float)cnt[i][j] + bias[n];
    }
  }
}

extern "C" void kernel_launch(void* const* d_in, const int* in_sizes, int n_in,
                              void* d_out, int out_size, void* d_ws, size_t ws_size,
                              hipStream_t stream) {
  const float* x = (const float*)d_in[0];
  const float* wgt = (const float*)d_in[1];
  const float* bias = (const float*)d_in[2];
  float* out = (float*)d_out;

  u64* Ap = (u64*)d_ws;                       // 4096*256*8 = 8 MB
  u64* Wp = Ap + (size_t)B_DIM * WORDS;       // 2048*256*8 = 4 MB

  // key(42) = (0,42); partitionable split: kA = tf((0,42),(0,0)), kB = tf((0,42),(0,1))
  uint32_t kA0, kA1, kB0, kB1;
  tf2x32(0u, 42u, 0u, 0u, &kA0, &kA1);
  tf2x32(0u, 42u, 0u, 1u, &kB0, &kB1);

  stoch_bits<<<B_DIM + N_DIM, 256, 0, stream>>>(x, wgt, Ap, Wp, kA0, kA1, kB0, kB1);
  dim3 grid(N_DIM / 64, B_DIM / 128);
  xnor_gemm<<<grid, 256, 0, stream>>>(Ap, Wp, bias, out);
  (void)in_sizes; (void)n_in; (void)out_size; (void)ws_size;
}

// Round 14
// 498.718 us; speedup vs baseline: 1.2063x; 1.0058x over previous
//
#include <hip/hip_runtime.h>
#include <stdint.h>

// StochLinear: out[b,n] = 2048 + 0.5*S - 0.25*(sA[b]+sB[n]) + bias[n]
//   S = sum_{l,k} a*b (0/1), sA/sB row bit-counts. Exact in f32.
// A/W bits: JAX threefry2x32, partitionable mode (bit-exact, rounds 2/5/8/9/11).
// B=4096, K=2048, N=2048, L=8 -> KL=16384 bytes per row (i8 path), 256 u64 (bit path).

#define B_DIM 4096
#define K_DIM 2048
#define N_DIM 2048
#define WORDS 256
#define KL 16384

typedef unsigned long long u64;
typedef int v4i __attribute__((ext_vector_type(4)));
typedef int v16i __attribute__((ext_vector_type(16)));

__host__ __device__ static inline void tf2x32(uint32_t ks0, uint32_t ks1,
                                              uint32_t x0, uint32_t x1,
                                              uint32_t* o0, uint32_t* o1) {
  uint32_t ks2 = ks0 ^ ks1 ^ 0x1BD11BDAu;
  x0 += ks0; x1 += ks1;
#define TF_RND(r) { x0 += x1; x1 = (x1 << (r)) | (x1 >> (32 - (r))); x1 ^= x0; }
  TF_RND(13) TF_RND(15) TF_RND(26) TF_RND(6)
  x0 += ks1; x1 += ks2 + 1u;
  TF_RND(17) TF_RND(29) TF_RND(16) TF_RND(24)
  x0 += ks2; x1 += ks0 + 2u;
  TF_RND(13) TF_RND(15) TF_RND(26) TF_RND(6)
  x0 += ks0; x1 += ks1 + 3u;
  TF_RND(17) TF_RND(29) TF_RND(16) TF_RND(24)
  x0 += ks1; x1 += ks2 + 4u;
  TF_RND(13) TF_RND(15) TF_RND(26) TF_RND(6)
  x0 += ks2; x1 += ks0 + 5u;
  *o0 = x0; *o1 = x1;
#undef TF_RND
}

// ======================= i8-MFMA path =======================

// Bit-gen -> byte matrices + row bit-counts.
// blocks [0,4096): x rows -> A8[b][l*2048+k], sA[b].
// blocks [4096,6144): weight rows -> W8[n][l*2048+k], sB[n].
// x elem (l,b,k): counter = l*2^23 + b*2048 + k; w elem (l,k,n): l*2^22 + k*2048 + n.
__global__ __launch_bounds__(256) void stoch_bytes(const float* __restrict__ x,
                                                   const float* __restrict__ wgt,
                                                   unsigned char* __restrict__ A8,
                                                   unsigned char* __restrict__ W8,
                                                   float* __restrict__ sA,
                                                   float* __restrict__ sB,
                                                   uint32_t xk0, uint32_t xk1,
                                                   uint32_t wk0, uint32_t wk1) {
  __shared__ unsigned int red[4];
  const unsigned blk = blockIdx.x;
  const bool isW = blk >= (unsigned)B_DIM;
  const unsigned row = isW ? (blk - (unsigned)B_DIM) : blk;
  const float* src = (isW ? wgt : x) + (size_t)row * K_DIM;
  unsigned char* dst = (isW ? W8 : A8) + (size_t)row * KL;
  const uint32_t k0 = isW ? wk0 : xk0;
  const uint32_t k1 = isW ? wk1 : xk1;
  const unsigned lane = threadIdx.x & 63u;
  const unsigned wv = threadIdx.x >> 6;
  unsigned int rs = 0;
#pragma unroll 1
  for (int i = 0; i < 8; ++i) {
    const unsigned kw = wv * 8u + (unsigned)i;
    const unsigned k = (kw << 6) + lane;
    const float v = src[k];
    const float p = fminf(fmaxf((v + 1.0f) * 0.5f, 0.0f), 1.0f);
    const float t = p * 8388608.0f;  // p*2^23 exact; u<p <=> (f32)(bits>>9) < t
    const uint32_t base = isW ? (k * 2048u + row) : (row * 2048u + k);
#pragma unroll
    for (int l = 0; l < 8; ++l) {
      uint32_t idx = base + (isW ? ((uint32_t)l << 22) : ((uint32_t)l << 23));
      uint32_t o0, o1;
      tf2x32(k0, k1, 0u, idx, &o0, &o1);
      uint32_t m = (o0 ^ o1) >> 9;
      bool bit = (float)m < t;
      dst[(unsigned)l * 2048u + k] = bit ? 1 : 0;
      u64 msk = __ballot(bit);
      rs += (unsigned)__popcll(msk);  // uniform across wave
    }
  }
  if (lane == 0) red[wv] = rs;
  __syncthreads();
  if (threadIdx.x == 0) {
    float tot = (float)(red[0] + red[1] + red[2] + red[3]);
    (isW ? sB : sA)[row] = tot;
  }
}

__device__ __forceinline__ void gload16(const void* g, void* l) {
  __builtin_amdgcn_global_load_lds((const __attribute__((address_space(1))) void*)g,
                                   (__attribute__((address_space(3))) void*)l, 16, 0, 0);
}

// i8 MFMA GEMM: 128x128 tile, 4 waves in 2x2, each wave 2x2 mfma tiles of 32x32.
// BK=64 bytes/step, 256 steps. LDS holds fragment-ordered A/B (8 blocks x 1024B each):
// block (r,s): lane l's 16 bytes = row r*32+(l&31), k = s*32+(l>>5)*16.. (k-order shared
// by A and B -> permutation-invariant). Staged via pre-swizzled global_load_lds sources;
// ds_read_b128 is lane-linear = conflict-free.
__global__ __launch_bounds__(256) void i8_gemm(const unsigned char* __restrict__ A8,
                                               const unsigned char* __restrict__ W8,
                                               const float* __restrict__ sA,
                                               const float* __restrict__ sB,
                                               const float* __restrict__ bias,
                                               float* __restrict__ out) {
  __shared__ unsigned char As[8192];
  __shared__ unsigned char Bs[8192];
  const int tid = threadIdx.x;
  const int l = tid & 63, wv = tid >> 6;
  const int wr = wv >> 1, wc = wv & 1;
  const int lr = l & 31, lh = l >> 5;
  int wg = (int)blockIdx.x;
  wg = (wg & 7) * 64 + (wg >> 3);          // XCD swizzle, bijective for 512
  const int bx = wg & 15, by = wg >> 4;    // 16 col-tiles x 32 row-tiles
  const int brow = by << 7, bcol = bx << 7;

  const unsigned char* pA[2];
  const unsigned char* pB[2];
#pragma unroll
  for (int i = 0; i < 2; ++i) {
    int gb = i * 4 + wv, r = gb >> 1, s = gb & 1;
    pA[i] = A8 + (size_t)(brow + r * 32 + lr) * KL + s * 32 + lh * 16;
    pB[i] = W8 + (size_t)(bcol + r * 32 + lr) * KL + s * 32 + lh * 16;
  }
  v16i acc[2][2] = {};
#pragma unroll 1
  for (int c = 0; c < 256; ++c) {
    if (c) __syncthreads();
    gload16(pA[0], As + wv * 1024);
    gload16(pA[1], As + 4096 + wv * 1024);
    gload16(pB[0], Bs + wv * 1024);
    gload16(pB[1], Bs + 4096 + wv * 1024);
    __syncthreads();
    v4i af[2][2], bf[2][2];
#pragma unroll
    for (int i = 0; i < 2; ++i)
#pragma unroll
      for (int s = 0; s < 2; ++s) {
        af[i][s] = *(const v4i*)(As + (((wr * 2 + i) * 2 + s) << 10) + l * 16);
        bf[i][s] = *(const v4i*)(Bs + (((wc * 2 + i) * 2 + s) << 10) + l * 16);
      }
#pragma unroll
    for (int s = 0; s < 2; ++s)
#pragma unroll
      for (int i = 0; i < 2; ++i)
#pragma unroll
        for (int j = 0; j < 2; ++j)
          acc[i][j] = __builtin_amdgcn_mfma_i32_32x32x32_i8(af[i][s], bf[j][s],
                                                            acc[i][j], 0, 0, 0);
    pA[0] += 64; pA[1] += 64; pB[0] += 64; pB[1] += 64;
  }
#pragma unroll
  for (int i = 0; i < 2; ++i)
#pragma unroll
    for (int j = 0; j < 2; ++j) {
      const int colb = bcol + wc * 64 + j * 32 + lr;
#pragma unroll
      for (int reg = 0; reg < 16; ++reg) {
        int rowb = brow + wr * 64 + i * 32 + (reg & 3) + ((reg >> 2) << 3) + (lh << 2);
        float S = (float)acc[i][j][reg];
        float val = (2048.0f + 0.5f * S - 0.25f * (sA[rowb] + sB[colb])) + bias[colb];
        out[(size_t)rowb * N_DIM + colb] = val;
      }
    }
}

// ======================= fallback binary path (round-11, verified) =======================

__global__ __launch_bounds__(256) void stoch_bits(const float* __restrict__ x,
                                                  const float* __restrict__ wgt,
                                                  u64* __restrict__ Ap,
                                                  u64* __restrict__ Wp,
                                                  uint32_t xk0, uint32_t xk1,
                                                  uint32_t wk0, uint32_t wk1) {
  const unsigned blk = blockIdx.x;
  const bool isW = blk >= (unsigned)B_DIM;
  const unsigned row = isW ? (blk - (unsigned)B_DIM) : blk;
  const float* src = (isW ? wgt : x) + (size_t)row * K_DIM;
  u64* dst = (isW ? Wp : Ap) + (size_t)row * WORDS;
  const uint32_t k0 = isW ? wk0 : xk0;
  const uint32_t k1 = isW ? wk1 : xk1;
  const unsigned lane = threadIdx.x & 63u;
  const unsigned wv = threadIdx.x >> 6;
#pragma unroll 1
  for (int i = 0; i < 8; ++i) {
    const unsigned kw = wv * 8u + (unsigned)i;
    const unsigned k = (kw << 6) + lane;
    const float v = src[k];
    const float p = fminf(fmaxf((v + 1.0f) * 0.5f, 0.0f), 1.0f);
    const float t = p * 8388608.0f;
    const uint32_t base = isW ? (k * 2048u + row) : (row * 2048u + k);
    u64 wbuf[8];
#pragma unroll
    for (int l = 0; l < 8; ++l) {
      uint32_t idx = base + (isW ? ((uint32_t)l << 22) : ((uint32_t)l << 23));
      uint32_t o0, o1;
      tf2x32(k0, k1, 0u, idx, &o0, &o1);
      uint32_t m = (o0 ^ o1) >> 9;
      wbuf[l] = __ballot((float)m < t);
    }
    if (lane == 0) {
#pragma unroll
      for (int l = 0; l < 8; ++l) dst[(l << 5) + kw] = wbuf[l];
    }
  }
}

__global__ __launch_bounds__(256, 4) void xnor_gemm(const u64* __restrict__ Ap,
                                                    const u64* __restrict__ Wp,
                                                    const float* __restrict__ bias,
                                                    float* __restrict__ out) {
  __shared__ u64 As[128][18];
  __shared__ u64 Ws[64][18];
  const int tid = threadIdx.x;
  const int brow = blockIdx.y << 7;
  const int bcol = blockIdx.x << 6;
  const int tx = tid & 15, ty = tid >> 4;
  uint32_t cnt[8][4] = {};
#pragma unroll 1
  for (int c = 0; c < 16; ++c) {
    if (c) __syncthreads();
#pragma unroll
    for (int i = 0; i < 4; ++i) {
      int q = tid + (i << 8);
      int r = q >> 3, c4 = q & 7;
      *(uint4*)&As[r][c4 << 1] =
          *(const uint4*)&Ap[(size_t)(brow + r) * WORDS + (c << 4) + (c4 << 1)];
    }
#pragma unroll
    for (int i = 0; i < 2; ++i) {
      int q = tid + (i << 8);
      int r = q >> 3, c4 = q & 7;
      *(uint4*)&Ws[r][c4 << 1] =
          *(const uint4*)&Wp[(size_t)(bcol + r) * WORDS + (c << 4) + (c4 << 1)];
    }
    __syncthreads();
#pragma unroll 2
    for (int wp = 0; wp < 8; ++wp) {
      uint4 av[8], bv[4];
#pragma unroll
      for (int i = 0; i < 8; ++i)
        av[i] = *(const uint4*)&As[ty + (i << 4)][wp << 1];
#pragma unroll
      for (int j = 0; j < 4; ++j)
        bv[j] = *(const uint4*)&Ws[tx + (j << 4)][wp << 1];
#pragma unroll
      for (int i = 0; i < 8; ++i)
#pragma unroll
        for (int j = 0; j < 4; ++j) {
          uint32_t t0 = av[i].x ^ bv[j].x;
          uint32_t t1 = av[i].y ^ bv[j].y;
          uint32_t t2 = av[i].z ^ bv[j].z;
          uint32_t t3 = av[i].w ^ bv[j].w;
          asm("v_bcnt_u32_b32 %0, %1, %0" : "+v"(cnt[i][j]) : "v"(t0));
          asm("v_bcnt_u32_b32 %0, %1, %0" : "+v"(cnt[i][j]) : "v"(t1));
          asm("v_bcnt_u32_b32 %0, %1, %0" : "+v"(cnt[i][j]) : "v"(t2));
          asm("v_bcnt_u32_b32 %0, %1, %0" : "+v"(cnt[i][j]) : "v"(t3));
        }
    }
  }
#pragma unroll
  for (int i = 0; i < 8; ++i) {
    int r = brow + ty + (i << 4);
#pragma unroll
    for (int j = 0; j < 4; ++j) {
      int n = bcol + tx + (j << 4);
      out[(size_t)r * N_DIM + n] = 2048.0f - 0.25f * (float)cnt[i][j] + bias[n];
    }
  }
}

extern "C" void kernel_launch(void* const* d_in, const int* in_sizes, int n_in,
                              void* d_out, int out_size, void* d_ws, size_t ws_size,
                              hipStream_t stream) {
  const float* x = (const float*)d_in[0];
  const float* wgt = (const float*)d_in[1];
  const float* bias = (const float*)d_in[2];
  float* out = (float*)d_out;

  uint32_t kA0, kA1, kB0, kB1;
  tf2x32(0u, 42u, 0u, 0u, &kA0, &kA1);
  tf2x32(0u, 42u, 0u, 1u, &kB0, &kB1);

  const size_t szA8 = (size_t)B_DIM * KL;            // 64 MB
  const size_t szW8 = (size_t)N_DIM * KL;            // 32 MB
  const size_t need = szA8 + szW8 + (B_DIM + N_DIM) * sizeof(float);

  if (ws_size >= need) {
    unsigned char* A8 = (unsigned char*)d_ws;
    unsigned char* W8 = A8 + szA8;
    float* sA = (float*)(W8 + szW8);
    float* sB = sA + B_DIM;
    stoch_bytes<<<B_DIM + N_DIM, 256, 0, stream>>>(x, wgt, A8, W8, sA, sB,
                                                   kA0, kA1, kB0, kB1);
    i8_gemm<<<512, 256, 0, stream>>>(A8, W8, sA, sB, bias, out);
  } else {
    u64* Ap = (u64*)d_ws;
    u64* Wp = Ap + (size_t)B_DIM * WORDS;
    stoch_bits<<<B_DIM + N_DIM, 256, 0, stream>>>(x, wgt, Ap, Wp, kA0, kA1, kB0, kB1);
    dim3 grid(N_DIM / 64, B_DIM / 128);
    xnor_gemm<<<grid, 256, 0, stream>>>(Ap, Wp, bias, out);
  }
  (void)in_sizes; (void)n_in; (void)out_size;
}